// Round 2
// baseline (883.037 us; speedup 1.0000x reference)
//
#include <hip/hip_runtime.h>
#include <cstdint>
#include <cstddef>

// Problem dims
#define B_ROWS 65536
#define D_IN   784
#define KP     800      // D_IN padded to multiple of 32
#define D_H    300
#define NP     320      // D_H padded to multiple of 64
#define D_OUT  10
#define NP2    16       // D_OUT padded to 16
#define EPS    1e-5f
#define NBLK1  1024     // 65536 / 64 rows per block

typedef _Float16 half8  __attribute__((ext_vector_type(8)));
typedef float    floatx4 __attribute__((ext_vector_type(4)));

// Workspace layout (bytes). part[] aliases oc[]: part is consumed by k_reduce
// BEFORE k_gemm2 writes oc (strictly ordered on one stream).
#define OFF_S1   ((size_t)0)                       // _Float16[320*800]   = 512000
#define OFF_H    ((size_t)512000)                  // _Float16[65536*320] = 41943040
#define OFF_ST1  (OFF_H + (size_t)41943040)        // float[640] sum+sumsq
#define OFF_W2   (OFF_ST1 + (size_t)2560)          // _Float16[16*320]    = 10240
#define OFF_ST2  (OFF_W2 + (size_t)10240)          // float[32] sum+sumsq
#define OFF_OC   (OFF_ST2 + (size_t)256)           // float[65536*16]     = 4194304
#define OFF_P1   OFF_OC                            // float[640][1024]    = 2621440 (alias)

// ---------------- K0: binarize W1 -> fp16 (+-1), zero-padded to [320][800]
__global__ void k_prep1(const float* __restrict__ W1, _Float16* __restrict__ S1)
{
    int idx = blockIdx.x * 256 + threadIdx.x;      // 0..255999
    int n = idx / KP;
    int k = idx - n * KP;
    float v = 0.0f;
    if (n < D_H && k < D_IN)
        v = (W1[n * D_IN + k] >= 0.0f) ? 1.0f : -1.0f;
    S1[idx] = (_Float16)v;
}

// ---------------- K1: h = x @ S1^T  (M=65536, N=320, K=800), fp16 MFMA
// Barrier-free / LDS-free: per-lane direct global->register fragment loads,
// explicit register double-buffer prefetch of K-step kk+32.
// Block 256 thr = 4 waves; block tile 64 rows x 320 cols (x read once from HBM,
// A-fragment re-reads across the 4 waves hit L1/L2). Wave w: cols [80w,80w+80).
// Fused: per-block column sum/sumsq partials of h (pre-rounding fp32 acc).
__global__ __launch_bounds__(256, 2) void k_gemm1(const float* __restrict__ x,
                                                  const _Float16* __restrict__ S1,
                                                  _Float16* __restrict__ h,
                                                  float* __restrict__ part)
{
    const int t     = threadIdx.x;
    const int wave  = t >> 6;
    const int lane  = t & 63;
    const int row15 = lane & 15;
    const int quad  = lane >> 4;
    const int m0    = blockIdx.x * 64;

    // per-lane fragment base pointers (MFMA A/B operand layout: lane holds
    // row=row15, k = quad*8 .. +8)
    const float*    xb = x  + (size_t)(m0 + row15) * D_IN + quad * 8;
    const _Float16* bb = S1 + (size_t)(wave * 80 + row15) * KP + quad * 8;

    floatx4 acc[4][5] = {};
    floatx4 av[2][8];      // [buf][mt*2 + half] : A fp32, 4 m-tiles x 8 floats
    half8   bv[2][5];      // [buf][nt]          : B fp16

    // prologue: kk = 0 (quad*8+8 <= 32 < 784, always valid)
#pragma unroll
    for (int mt = 0; mt < 4; ++mt) {
        const float* p = xb + (size_t)mt * 16 * D_IN;
        av[0][mt * 2]     = *(const floatx4*)(p);
        av[0][mt * 2 + 1] = *(const floatx4*)(p + 4);
    }
#pragma unroll
    for (int nt = 0; nt < 5; ++nt)
        bv[0][nt] = *(const half8*)(bb + (size_t)nt * 16 * KP);

    int buf = 0;
    for (int kk = 0; kk < KP; kk += 32) {
        const int nk = kk + 32;
        if (nk < KP) {
            // prefetch next K-step into the other buffer.
            // 8-chunk fully valid iff nk+quad*8 < 784 (784 % 8 == 0); the
            // invalid tail (kk=768, quads 2,3) is zero-filled; S1 pad is zero.
            const bool ok = (nk + quad * 8) < D_IN;
#pragma unroll
            for (int mt = 0; mt < 4; ++mt) {
                floatx4 v0 = {}, v1 = {};
                if (ok) {
                    const float* p = xb + (size_t)mt * 16 * D_IN + nk;
                    v0 = *(const floatx4*)(p);
                    v1 = *(const floatx4*)(p + 4);
                }
                av[buf ^ 1][mt * 2]     = v0;
                av[buf ^ 1][mt * 2 + 1] = v1;
            }
#pragma unroll
            for (int nt = 0; nt < 5; ++nt)
                bv[buf ^ 1][nt] = *(const half8*)(bb + (size_t)nt * 16 * KP + nk);
        }
        // convert current A buffer fp32 -> fp16 fragments
        half8 a[4];
#pragma unroll
        for (int mt = 0; mt < 4; ++mt) {
#pragma unroll
            for (int i = 0; i < 4; ++i) {
                a[mt][i]     = (_Float16)av[buf][mt * 2][i];
                a[mt][4 + i] = (_Float16)av[buf][mt * 2 + 1][i];
            }
        }
#pragma unroll
        for (int nt = 0; nt < 5; ++nt)
#pragma unroll
            for (int mt = 0; mt < 4; ++mt)
                acc[mt][nt] = __builtin_amdgcn_mfma_f32_16x16x32_f16(a[mt], bv[buf][nt], acc[mt][nt], 0, 0, 0);
        buf ^= 1;
    }

    // --- epilogue: store h (C/D layout: col=lane&15, row=quad*4+r) + stats
    float s[5] = {}, q[5] = {};
#pragma unroll
    for (int mt = 0; mt < 4; ++mt)
#pragma unroll
        for (int nt = 0; nt < 5; ++nt)
#pragma unroll
            for (int r = 0; r < 4; ++r) {
                float v = acc[mt][nt][r];
                int m = m0 + mt * 16 + quad * 4 + r;
                int n = wave * 80 + nt * 16 + row15;
                h[(size_t)m * NP + n] = (_Float16)v;
                s[nt] += v;
                q[nt] += v * v;
            }
    // reduce over quad (waves own disjoint col ranges -> no cross-wave combine)
#pragma unroll
    for (int nt = 0; nt < 5; ++nt) {
        s[nt] += __shfl_xor(s[nt], 16); s[nt] += __shfl_xor(s[nt], 32);
        q[nt] += __shfl_xor(q[nt], 16); q[nt] += __shfl_xor(q[nt], 32);
    }
    if (quad == 0) {
#pragma unroll
        for (int nt = 0; nt < 5; ++nt) {
            int col = wave * 80 + nt * 16 + row15;
            part[(size_t)col * NBLK1 + blockIdx.x]         = s[nt];
            part[(size_t)(NP + col) * NBLK1 + blockIdx.x]  = q[nt];
        }
    }
}

// ---------------- K2: contention-free reduce of per-block partials -> st1[640]
__global__ void k_reduce(const float* __restrict__ part, float* __restrict__ st1)
{
    __shared__ float red[4];
    const int c = blockIdx.x;            // 0..639
    const int t = threadIdx.x;           // 256
    const float* p = part + (size_t)c * NBLK1;
    float s = p[t] + p[t + 256] + p[t + 512] + p[t + 768];
#pragma unroll
    for (int off = 1; off < 64; off <<= 1) s += __shfl_xor(s, off);
    if ((t & 63) == 0) red[t >> 6] = s;
    __syncthreads();
    if (t == 0) st1[c] = red[0] + red[1] + red[2] + red[3];
}

// ---------------- K3: fold BN1 scale into binarized W2 -> w2h[16][320] fp16
__global__ void k_prep2(const float* __restrict__ st, const float* __restrict__ gamma1,
                        const float* __restrict__ W2, _Float16* __restrict__ w2h)
{
    int j = threadIdx.x;                 // 0..319
    float mean = st[j] * (1.0f / 65536.0f);
    float var  = st[NP + j] * (1.0f / 65536.0f) - mean * mean;
    float a1   = 0.0f;
    if (j < D_H) a1 = gamma1[j] / sqrtf(var + EPS);
    for (int k = 0; k < NP2; ++k) {
        float w = 0.0f;
        if (k < D_OUT && j < D_H)
            w = (W2[k * D_H + j] >= 0.0f) ? a1 : -a1;
        w2h[k * NP + j] = (_Float16)w;
    }
}

// ---------------- K4: oc = h @ w2h^T  (K=320, N=16) + fused column stats of oc
__global__ __launch_bounds__(256) void k_gemm2(const _Float16* __restrict__ h,
                                               const _Float16* __restrict__ w2h,
                                               float* __restrict__ oc,
                                               float* __restrict__ st2)
{
    __shared__ _Float16 Wlds[16][328];   // pad 320->328 to break bank conflicts
    __shared__ float reds[4][16], redq[4][16];
    const int t     = threadIdx.x;
    const int wave  = t >> 6;
    const int lane  = t & 63;
    const int row15 = lane & 15;
    const int quad  = lane >> 4;

    for (int c = t; c < 640; c += 256) { // 16*320/8 chunks
        int r  = c / 40;
        int cc = (c - r * 40) * 8;
        *(half8*)&Wlds[r][cc] = *(const half8*)(w2h + r * NP + cc);
    }
    __syncthreads();

    const int m0 = blockIdx.x * 64 + wave * 16;
    const _Float16* hp = h + (size_t)(m0 + row15) * NP + quad * 8;
    floatx4 acc = {};
#pragma unroll
    for (int kk = 0; kk < NP; kk += 32) {
        half8 a = *(const half8*)(hp + kk);
        half8 b = *(const half8*)&Wlds[row15][kk + quad * 8];
        acc = __builtin_amdgcn_mfma_f32_16x16x32_f16(a, b, acc, 0, 0, 0);
    }
    float s = 0.f, q = 0.f;
#pragma unroll
    for (int r = 0; r < 4; ++r) {
        float v = acc[r];
        oc[(size_t)(m0 + quad * 4 + r) * NP2 + row15] = v;
        s += v; q += v * v;
    }
    s += __shfl_xor(s, 16); s += __shfl_xor(s, 32);
    q += __shfl_xor(q, 16); q += __shfl_xor(q, 32);
    if (lane < 16) { reds[wave][row15] = s; redq[wave][row15] = q; }
    __syncthreads();
    if (t < 16) {
        float S = reds[0][t] + reds[1][t] + reds[2][t] + reds[3][t];
        float Q = redq[0][t] + redq[1][t] + redq[2][t] + redq[3][t];
        atomicAdd(&st2[t], S);
        atomicAdd(&st2[16 + t], Q);
    }
}

// ---------------- K5: BN2 epilogue -> out[65536][10] fp32
__global__ void k_final(const float* __restrict__ oc, const float* __restrict__ st2,
                        const float* __restrict__ gamma2, const float* __restrict__ beta2,
                        float* __restrict__ out)
{
    int idx = blockIdx.x * 256 + threadIdx.x;    // 2560*256 == 655360 exactly
    int m = idx / 10;
    int k = idx - m * 10;
    float mean = st2[k] * (1.0f / 65536.0f);
    float var  = st2[16 + k] * (1.0f / 65536.0f) - mean * mean;
    float sc   = gamma2[k] / sqrtf(var + EPS);
    out[idx] = (oc[(size_t)m * NP2 + k] - mean) * sc + beta2[k];
}

extern "C" void kernel_launch(void* const* d_in, const int* in_sizes, int n_in,
                              void* d_out, int out_size, void* d_ws, size_t ws_size,
                              hipStream_t stream)
{
    const float* x      = (const float*)d_in[0];
    const float* W1     = (const float*)d_in[1];
    const float* gamma1 = (const float*)d_in[2];
    // d_in[3] = beta1 : algebraically cancels under BN2's mean subtraction
    const float* W2     = (const float*)d_in[4];
    const float* gamma2 = (const float*)d_in[5];
    const float* beta2  = (const float*)d_in[6];
    float* out = (float*)d_out;

    char* ws = (char*)d_ws;
    _Float16* S1   = (_Float16*)(ws + OFF_S1);
    _Float16* h    = (_Float16*)(ws + OFF_H);
    float*    st1  = (float*)(ws + OFF_ST1);
    _Float16* w2h  = (_Float16*)(ws + OFF_W2);
    float*    st2  = (float*)(ws + OFF_ST2);
    float*    oc   = (float*)(ws + OFF_OC);
    float*    part = (float*)(ws + OFF_P1);   // aliases oc (time-disjoint)

    hipMemsetAsync(st2, 0, 32 * sizeof(float), stream);

    k_prep1 <<<1000, 256, 0, stream>>>(W1, S1);
    k_gemm1 <<<NBLK1, 256, 0, stream>>>(x, S1, h, part);
    k_reduce<<<640, 256, 0, stream>>>(part, st1);
    k_prep2 <<<1, 320, 0, stream>>>(st1, gamma1, W2, w2h);
    k_gemm2 <<<1024, 256, 0, stream>>>(h, w2h, oc, st2);
    k_final <<<2560, 256, 0, stream>>>(oc, st2, gamma2, beta2, out);
}

// Round 3
// 423.745 us; speedup vs baseline: 2.0839x; 2.0839x over previous
//
#include <hip/hip_runtime.h>
#include <cstdint>
#include <cstddef>

// Problem dims
#define B_ROWS 65536
#define D_IN   784
#define KP     800      // D_IN padded to multiple of 32
#define D_H    300
#define NP     320      // D_H padded to multiple of 64
#define D_OUT  10
#define NP2    16       // D_OUT padded to 16
#define EPS    1e-5f
#define NBLK1  1024     // 65536 / 64 rows per block

typedef _Float16 half8  __attribute__((ext_vector_type(8)));
typedef float    floatx4 __attribute__((ext_vector_type(4)));

// Workspace layout (bytes). part[] aliases oc[]: part is consumed by k_reduce
// BEFORE k_gemm2 writes oc (strictly ordered on one stream).
#define OFF_S1   ((size_t)0)                       // _Float16[320*800]   = 512000
#define OFF_H    ((size_t)512000)                  // _Float16[65536*320] = 41943040
#define OFF_ST1  (OFF_H + (size_t)41943040)        // float[640] sum+sumsq
#define OFF_W2   (OFF_ST1 + (size_t)2560)          // _Float16[16*320]    = 10240
#define OFF_ST2  (OFF_W2 + (size_t)10240)          // float[32] sum+sumsq
#define OFF_OC   (OFF_ST2 + (size_t)256)           // float[65536*16]     = 4194304
#define OFF_P1   OFF_OC                            // float[640][1024]    = 2621440 (alias)

// ---------------- K0: binarize W1 -> fp16 (+-1), zero-padded to [320][800]
__global__ void k_prep1(const float* __restrict__ W1, _Float16* __restrict__ S1)
{
    int idx = blockIdx.x * 256 + threadIdx.x;      // 0..255999
    int n = idx / KP;
    int k = idx - n * KP;
    float v = 0.0f;
    if (n < D_H && k < D_IN)
        v = (W1[n * D_IN + k] >= 0.0f) ? 1.0f : -1.0f;
    S1[idx] = (_Float16)v;
}

// ---------------- K1: h = x @ S1^T  (M=65536, N=320, K=800), fp16 MFMA
// Barrier-free / LDS-free: per-lane direct global->register fragment loads.
// COMPILE-TIME register double-buffer (two named sets, manual 2x unroll) —
// runtime-indexed buffers spill to scratch (R2 post-mortem: 1.37 GB scratch
// writes matched 208 B/thr/step exactly). 25 K-steps = 12 pairs + 1 tail.
// Block 256 thr = 4 waves; tile 64 rows x 320 cols. Wave w: cols [80w,80w+80).
// Fused: per-block column sum/sumsq partials of h.

#define PF_A(AV, NK)                                                        \
    {                                                                       \
        const bool ok = ((NK) + quad * 8) < D_IN;                           \
        _Pragma("unroll")                                                   \
        for (int mt = 0; mt < 4; ++mt) {                                    \
            floatx4 v0 = {}, v1 = {};                                       \
            if (ok) {                                                       \
                const float* p = xb + (size_t)mt * 16 * D_IN + (NK);        \
                v0 = *(const floatx4*)(p);                                  \
                v1 = *(const floatx4*)(p + 4);                              \
            }                                                               \
            AV[mt * 2]     = v0;                                            \
            AV[mt * 2 + 1] = v1;                                            \
        }                                                                   \
    }

#define PF_B(BV, NK)                                                        \
    _Pragma("unroll")                                                       \
    for (int nt = 0; nt < 5; ++nt)                                          \
        BV[nt] = *(const half8*)(bb + (size_t)nt * 16 * KP + (NK));

#define COMPUTE(AV, BV)                                                     \
    {                                                                       \
        half8 a[4];                                                         \
        _Pragma("unroll")                                                   \
        for (int mt = 0; mt < 4; ++mt) {                                    \
            _Pragma("unroll")                                               \
            for (int i = 0; i < 4; ++i) {                                   \
                a[mt][i]     = (_Float16)AV[mt * 2][i];                     \
                a[mt][4 + i] = (_Float16)AV[mt * 2 + 1][i];                 \
            }                                                               \
        }                                                                   \
        _Pragma("unroll")                                                   \
        for (int nt = 0; nt < 5; ++nt)                                      \
            _Pragma("unroll")                                               \
            for (int mt = 0; mt < 4; ++mt)                                  \
                acc[mt][nt] = __builtin_amdgcn_mfma_f32_16x16x32_f16(       \
                    a[mt], BV[nt], acc[mt][nt], 0, 0, 0);                   \
    }

__global__ __launch_bounds__(256) void k_gemm1(const float* __restrict__ x,
                                               const _Float16* __restrict__ S1,
                                               _Float16* __restrict__ h,
                                               float* __restrict__ part)
{
    const int t     = threadIdx.x;
    const int wave  = t >> 6;
    const int lane  = t & 63;
    const int row15 = lane & 15;
    const int quad  = lane >> 4;
    const int m0    = blockIdx.x * 64;

    // per-lane fragment base pointers (MFMA A/B operand layout: lane holds
    // row=row15, k = quad*8 .. +8)
    const float*    xb = x  + (size_t)(m0 + row15) * D_IN + quad * 8;
    const _Float16* bb = S1 + (size_t)(wave * 80 + row15) * KP + quad * 8;

    floatx4 acc[4][5] = {};
    floatx4 a0[8], a1[8];
    half8   b0[5], b1[5];

    PF_A(a0, 0)
    PF_B(b0, 0)

    for (int i = 0; i < 12; ++i) {
        const int kk = i * 64;
        PF_A(a1, kk + 32)
        PF_B(b1, kk + 32)
        COMPUTE(a0, b0)
        PF_A(a0, kk + 64)
        PF_B(b0, kk + 64)
        COMPUTE(a1, b1)
    }
    COMPUTE(a0, b0)    // kk = 768 (tail; quads 2,3 zero-padded by PF_A guard)

    // --- epilogue: store h (C/D layout: col=lane&15, row=quad*4+r) + stats
    float s[5] = {}, q[5] = {};
#pragma unroll
    for (int mt = 0; mt < 4; ++mt)
#pragma unroll
        for (int nt = 0; nt < 5; ++nt)
#pragma unroll
            for (int r = 0; r < 4; ++r) {
                float v = acc[mt][nt][r];
                int m = m0 + mt * 16 + quad * 4 + r;
                int n = wave * 80 + nt * 16 + row15;
                h[(size_t)m * NP + n] = (_Float16)v;
                s[nt] += v;
                q[nt] += v * v;
            }
    // reduce over quad (waves own disjoint col ranges -> no cross-wave combine)
#pragma unroll
    for (int nt = 0; nt < 5; ++nt) {
        s[nt] += __shfl_xor(s[nt], 16); s[nt] += __shfl_xor(s[nt], 32);
        q[nt] += __shfl_xor(q[nt], 16); q[nt] += __shfl_xor(q[nt], 32);
    }
    if (quad == 0) {
#pragma unroll
        for (int nt = 0; nt < 5; ++nt) {
            int col = wave * 80 + nt * 16 + row15;
            part[(size_t)col * NBLK1 + blockIdx.x]         = s[nt];
            part[(size_t)(NP + col) * NBLK1 + blockIdx.x]  = q[nt];
        }
    }
}

// ---------------- K2: contention-free reduce of per-block partials -> st1[640]
__global__ void k_reduce(const float* __restrict__ part, float* __restrict__ st1)
{
    __shared__ float red[4];
    const int c = blockIdx.x;            // 0..639
    const int t = threadIdx.x;           // 256
    const float* p = part + (size_t)c * NBLK1;
    float s = p[t] + p[t + 256] + p[t + 512] + p[t + 768];
#pragma unroll
    for (int off = 1; off < 64; off <<= 1) s += __shfl_xor(s, off);
    if ((t & 63) == 0) red[t >> 6] = s;
    __syncthreads();
    if (t == 0) st1[c] = red[0] + red[1] + red[2] + red[3];
}

// ---------------- K3: fold BN1 scale into binarized W2 -> w2h[16][320] fp16
__global__ void k_prep2(const float* __restrict__ st, const float* __restrict__ gamma1,
                        const float* __restrict__ W2, _Float16* __restrict__ w2h)
{
    int j = threadIdx.x;                 // 0..319
    float mean = st[j] * (1.0f / 65536.0f);
    float var  = st[NP + j] * (1.0f / 65536.0f) - mean * mean;
    float a1   = 0.0f;
    if (j < D_H) a1 = gamma1[j] / sqrtf(var + EPS);
    for (int k = 0; k < NP2; ++k) {
        float w = 0.0f;
        if (k < D_OUT && j < D_H)
            w = (W2[k * D_H + j] >= 0.0f) ? a1 : -a1;
        w2h[k * NP + j] = (_Float16)w;
    }
}

// ---------------- K4: oc = h @ w2h^T  (K=320, N=16) + fused column stats of oc
__global__ __launch_bounds__(256) void k_gemm2(const _Float16* __restrict__ h,
                                               const _Float16* __restrict__ w2h,
                                               float* __restrict__ oc,
                                               float* __restrict__ st2)
{
    __shared__ _Float16 Wlds[16][328];   // pad 320->328 to break bank conflicts
    __shared__ float reds[4][16], redq[4][16];
    const int t     = threadIdx.x;
    const int wave  = t >> 6;
    const int lane  = t & 63;
    const int row15 = lane & 15;
    const int quad  = lane >> 4;

    for (int c = t; c < 640; c += 256) { // 16*320/8 chunks
        int r  = c / 40;
        int cc = (c - r * 40) * 8;
        *(half8*)&Wlds[r][cc] = *(const half8*)(w2h + r * NP + cc);
    }
    __syncthreads();

    const int m0 = blockIdx.x * 64 + wave * 16;
    const _Float16* hp = h + (size_t)(m0 + row15) * NP + quad * 8;
    floatx4 acc = {};
#pragma unroll
    for (int kk = 0; kk < NP; kk += 32) {
        half8 a = *(const half8*)(hp + kk);
        half8 b = *(const half8*)&Wlds[row15][kk + quad * 8];
        acc = __builtin_amdgcn_mfma_f32_16x16x32_f16(a, b, acc, 0, 0, 0);
    }
    float s = 0.f, q = 0.f;
#pragma unroll
    for (int r = 0; r < 4; ++r) {
        float v = acc[r];
        oc[(size_t)(m0 + quad * 4 + r) * NP2 + row15] = v;
        s += v; q += v * v;
    }
    s += __shfl_xor(s, 16); s += __shfl_xor(s, 32);
    q += __shfl_xor(q, 16); q += __shfl_xor(q, 32);
    if (lane < 16) { reds[wave][row15] = s; redq[wave][row15] = q; }
    __syncthreads();
    if (t < 16) {
        float S = reds[0][t] + reds[1][t] + reds[2][t] + reds[3][t];
        float Q = redq[0][t] + redq[1][t] + redq[2][t] + redq[3][t];
        atomicAdd(&st2[t], S);
        atomicAdd(&st2[16 + t], Q);
    }
}

// ---------------- K5: BN2 epilogue -> out[65536][10] fp32
__global__ void k_final(const float* __restrict__ oc, const float* __restrict__ st2,
                        const float* __restrict__ gamma2, const float* __restrict__ beta2,
                        float* __restrict__ out)
{
    int idx = blockIdx.x * 256 + threadIdx.x;    // 2560*256 == 655360 exactly
    int m = idx / 10;
    int k = idx - m * 10;
    float mean = st2[k] * (1.0f / 65536.0f);
    float var  = st2[16 + k] * (1.0f / 65536.0f) - mean * mean;
    float sc   = gamma2[k] / sqrtf(var + EPS);
    out[idx] = (oc[(size_t)m * NP2 + k] - mean) * sc + beta2[k];
}

extern "C" void kernel_launch(void* const* d_in, const int* in_sizes, int n_in,
                              void* d_out, int out_size, void* d_ws, size_t ws_size,
                              hipStream_t stream)
{
    const float* x      = (const float*)d_in[0];
    const float* W1     = (const float*)d_in[1];
    const float* gamma1 = (const float*)d_in[2];
    // d_in[3] = beta1 : algebraically cancels under BN2's mean subtraction
    const float* W2     = (const float*)d_in[4];
    const float* gamma2 = (const float*)d_in[5];
    const float* beta2  = (const float*)d_in[6];
    float* out = (float*)d_out;

    char* ws = (char*)d_ws;
    _Float16* S1   = (_Float16*)(ws + OFF_S1);
    _Float16* h    = (_Float16*)(ws + OFF_H);
    float*    st1  = (float*)(ws + OFF_ST1);
    _Float16* w2h  = (_Float16*)(ws + OFF_W2);
    float*    st2  = (float*)(ws + OFF_ST2);
    float*    oc   = (float*)(ws + OFF_OC);
    float*    part = (float*)(ws + OFF_P1);   // aliases oc (time-disjoint)

    hipMemsetAsync(st2, 0, 32 * sizeof(float), stream);

    k_prep1 <<<1000, 256, 0, stream>>>(W1, S1);
    k_gemm1 <<<NBLK1, 256, 0, stream>>>(x, S1, h, part);
    k_reduce<<<640, 256, 0, stream>>>(part, st1);
    k_prep2 <<<1, 320, 0, stream>>>(st1, gamma1, W2, w2h);
    k_gemm2 <<<1024, 256, 0, stream>>>(h, w2h, oc, st2);
    k_final <<<2560, 256, 0, stream>>>(oc, st2, gamma2, beta2, out);
}

// Round 4
// 350.623 us; speedup vs baseline: 2.5185x; 1.2086x over previous
//
#include <hip/hip_runtime.h>
#include <cstdint>
#include <cstddef>

// Problem dims
#define B_ROWS 65536
#define D_IN   784
#define KP     800      // D_IN padded to multiple of 32
#define D_H    300
#define NP     320      // D_H padded to multiple of 64
#define D_OUT  10
#define NP2    16       // D_OUT padded to 16
#define EPS    1e-5f
#define NBLK   1024     // blocks in gemm1 and gemm2 grids
#define APAD   44       // LDS A row stride in halfs (44*2=88 B -> <=2-way banks)

typedef _Float16 half8  __attribute__((ext_vector_type(8)));
typedef float    floatx4 __attribute__((ext_vector_type(4)));

// Workspace layout (bytes). part[] aliases oc[]: part is consumed by k_reduce
// BEFORE k_gemm2 writes oc (strictly ordered on one stream).
#define OFF_S1   ((size_t)0)                       // _Float16[320*800]   = 512000
#define OFF_H    ((size_t)512000)                  // _Float16[65536*320] = 41943040
#define OFF_ST1  (OFF_H + (size_t)41943040)        // float[640]
#define OFF_W2   (OFF_ST1 + (size_t)2560)          // _Float16[16*320]    = 10240
#define OFF_ST2  (OFF_W2 + (size_t)10240)          // float[32]
#define OFF_OC   (OFF_ST2 + (size_t)256)           // float[65536*16]     = 4194304
#define OFF_P1   OFF_OC                            // float[640][1024] (alias, time-disjoint)
#define OFF_P2   (OFF_OC + (size_t)4194304)        // float[32][1024]     = 131072

// ---------------- K0: binarize W1 -> fp16 (+-1), zero-padded to [320][800]
__global__ void k_prep1(const float* __restrict__ W1, _Float16* __restrict__ S1)
{
    int idx = blockIdx.x * 256 + threadIdx.x;      // 0..255999
    int n = idx / KP;
    int k = idx - n * KP;
    float v = 0.0f;
    if (n < D_H && k < D_IN)
        v = (W1[n * D_IN + k] >= 0.0f) ? 1.0f : -1.0f;
    S1[idx] = (_Float16)v;
}

// ---------------- K1: h = x @ S1^T  (M=65536, N=320, K=800), fp16 MFMA
// A staged ONCE per block into double-buffered LDS (fp32 load -> cvt -> fp16
// ds_write), one barrier per 32-wide K-step; A-frags via ds_read_b128 from
// padded rows (stride 44 halfs). B (L2-resident 512 KB) prefetched into
// compile-time ping-pong register sets. VMEM: 7 loads/thread/step (was 13,
// with 4x redundant A). Fused per-block column sum/sumsq partials of h.

#define PF_B(BV, NK)                                                        \
    _Pragma("unroll")                                                       \
    for (int nt = 0; nt < 5; ++nt)                                          \
        BV[nt] = *(const half8*)(bb + (size_t)nt * 16 * KP + (NK));

#define STAGE_LOAD(KK)                                                      \
    {                                                                       \
        sv0 = (floatx4){}; sv1 = (floatx4){};                               \
        if ((KK) + sc < D_IN) {            /* chunk-uniform: D_IN%8==0 */   \
            sv0 = *(const floatx4*)(sxp + (KK));                            \
            sv1 = *(const floatx4*)(sxp + (KK) + 4);                        \
        }                                                                   \
    }

#define STAGE_STORE(BUF)                                                    \
    {                                                                       \
        half8 hv;                                                           \
        _Pragma("unroll")                                                   \
        for (int i2 = 0; i2 < 4; ++i2) {                                    \
            hv[i2]     = (_Float16)sv0[i2];                                 \
            hv[4 + i2] = (_Float16)sv1[i2];                                 \
        }                                                                   \
        *(half8*)&Alds[BUF][srow][sc] = hv;                                 \
    }

#define AFRAG(BUF)                                                          \
    _Pragma("unroll")                                                       \
    for (int mt = 0; mt < 4; ++mt)                                          \
        a[mt] = *(const half8*)&Alds[BUF][mt * 16 + row15][quad * 8];

#define COMPUTE(BV)                                                         \
    _Pragma("unroll")                                                       \
    for (int nt = 0; nt < 5; ++nt)                                          \
        _Pragma("unroll")                                                   \
        for (int mt = 0; mt < 4; ++mt)                                      \
            acc[mt][nt] = __builtin_amdgcn_mfma_f32_16x16x32_f16(           \
                a[mt], BV[nt], acc[mt][nt], 0, 0, 0);

__global__ __launch_bounds__(256) void k_gemm1(const float* __restrict__ x,
                                               const _Float16* __restrict__ S1,
                                               _Float16* __restrict__ h,
                                               float* __restrict__ part)
{
    __shared__ _Float16 Alds[2][64][APAD];   // 2 x 5.5 KB
    const int t     = threadIdx.x;
    const int wave  = t >> 6;
    const int lane  = t & 63;
    const int row15 = lane & 15;
    const int quad  = lane >> 4;
    const int m0    = blockIdx.x * 64;

    // staging assignment: thread t -> row t>>2, half-chunk (t&3)*8
    const int srow = t >> 2;
    const int sc   = (t & 3) * 8;
    const float* sxp = x + (size_t)(m0 + srow) * D_IN + sc;

    // B fragment base (MFMA B layout: lane holds col=row15, k=quad*8..+8)
    const _Float16* bb = S1 + (size_t)(wave * 80 + row15) * KP + quad * 8;

    floatx4 acc[4][5] = {};
    half8   b0[5], b1[5];
    half8   a[4];
    floatx4 sv0, sv1;

    STAGE_LOAD(0)
    STAGE_STORE(0)
    PF_B(b0, 0)
    __syncthreads();

    for (int i = 0; i < 12; ++i) {
        const int kk = i * 64;
        // even step 2i: reads Alds[0] / b0; stages step 2i+1 -> Alds[1]
        STAGE_LOAD(kk + 32)
        PF_B(b1, kk + 32)
        AFRAG(0)
        COMPUTE(b0)
        STAGE_STORE(1)
        __syncthreads();
        // odd step 2i+1: reads Alds[1] / b1; stages step 2i+2 -> Alds[0]
        STAGE_LOAD(kk + 64)            // i=11 -> 768 (tail chunks zero-padded)
        PF_B(b0, kk + 64)
        AFRAG(1)
        COMPUTE(b1)
        STAGE_STORE(0)
        __syncthreads();
    }
    // tail step 24: reads Alds[0] / b0
    AFRAG(0)
    COMPUTE(b0)

    // --- epilogue: store h (C/D layout: col=lane&15, row=quad*4+r) + stats
    float s[5] = {}, q[5] = {};
#pragma unroll
    for (int mt = 0; mt < 4; ++mt)
#pragma unroll
        for (int nt = 0; nt < 5; ++nt)
#pragma unroll
            for (int r = 0; r < 4; ++r) {
                float v = acc[mt][nt][r];
                int m = m0 + mt * 16 + quad * 4 + r;
                int n = wave * 80 + nt * 16 + row15;
                h[(size_t)m * NP + n] = (_Float16)v;
                s[nt] += v;
                q[nt] += v * v;
            }
    // reduce over quad (waves own disjoint col ranges -> no cross-wave combine)
#pragma unroll
    for (int nt = 0; nt < 5; ++nt) {
        s[nt] += __shfl_xor(s[nt], 16); s[nt] += __shfl_xor(s[nt], 32);
        q[nt] += __shfl_xor(q[nt], 16); q[nt] += __shfl_xor(q[nt], 32);
    }
    if (quad == 0) {
#pragma unroll
        for (int nt = 0; nt < 5; ++nt) {
            int col = wave * 80 + nt * 16 + row15;
            part[(size_t)col * NBLK + blockIdx.x]        = s[nt];
            part[(size_t)(NP + col) * NBLK + blockIdx.x] = q[nt];
        }
    }
}

// ---------------- K2: contention-free reduce of per-block partials
// (one block per output element; partial stride fixed at NBLK=1024)
__global__ void k_reduce(const float* __restrict__ part, float* __restrict__ st)
{
    __shared__ float red[4];
    const int c = blockIdx.x;
    const int t = threadIdx.x;           // 256
    const float* p = part + (size_t)c * NBLK;
    float s = p[t] + p[t + 256] + p[t + 512] + p[t + 768];
#pragma unroll
    for (int off = 1; off < 64; off <<= 1) s += __shfl_xor(s, off);
    if ((t & 63) == 0) red[t >> 6] = s;
    __syncthreads();
    if (t == 0) st[c] = red[0] + red[1] + red[2] + red[3];
}

// ---------------- K3: fold BN1 scale into binarized W2 -> w2h[16][320] fp16
__global__ void k_prep2(const float* __restrict__ st, const float* __restrict__ gamma1,
                        const float* __restrict__ W2, _Float16* __restrict__ w2h)
{
    int j = threadIdx.x;                 // 0..319
    float mean = st[j] * (1.0f / 65536.0f);
    float var  = st[NP + j] * (1.0f / 65536.0f) - mean * mean;
    float a1   = 0.0f;
    if (j < D_H) a1 = gamma1[j] / sqrtf(var + EPS);
    for (int k = 0; k < NP2; ++k) {
        float w = 0.0f;
        if (k < D_OUT && j < D_H)
            w = (W2[k * D_H + j] >= 0.0f) ? a1 : -a1;
        w2h[k * NP + j] = (_Float16)w;
    }
}

// ---------------- K4: oc = h @ w2h^T  (K=320, N=16) + per-block stat partials
__global__ __launch_bounds__(256) void k_gemm2(const _Float16* __restrict__ h,
                                               const _Float16* __restrict__ w2h,
                                               float* __restrict__ oc,
                                               float* __restrict__ part2)
{
    __shared__ _Float16 Wlds[16][328];   // pad 320->328 to break bank conflicts
    __shared__ float reds[4][16], redq[4][16];
    const int t     = threadIdx.x;
    const int wave  = t >> 6;
    const int lane  = t & 63;
    const int row15 = lane & 15;
    const int quad  = lane >> 4;

    for (int c = t; c < 640; c += 256) { // 16*320/8 chunks
        int r  = c / 40;
        int cc = (c - r * 40) * 8;
        *(half8*)&Wlds[r][cc] = *(const half8*)(w2h + r * NP + cc);
    }
    __syncthreads();

    const int m0 = blockIdx.x * 64 + wave * 16;
    const _Float16* hp = h + (size_t)(m0 + row15) * NP + quad * 8;
    floatx4 acc = {};
#pragma unroll
    for (int kk = 0; kk < NP; kk += 32) {
        half8 a2 = *(const half8*)(hp + kk);
        half8 b2 = *(const half8*)&Wlds[row15][kk + quad * 8];
        acc = __builtin_amdgcn_mfma_f32_16x16x32_f16(a2, b2, acc, 0, 0, 0);
    }
    float s = 0.f, q = 0.f;
#pragma unroll
    for (int r = 0; r < 4; ++r) {
        float v = acc[r];
        oc[(size_t)(m0 + quad * 4 + r) * NP2 + row15] = v;
        s += v; q += v * v;
    }
    s += __shfl_xor(s, 16); s += __shfl_xor(s, 32);
    q += __shfl_xor(q, 16); q += __shfl_xor(q, 32);
    if (lane < 16) { reds[wave][row15] = s; redq[wave][row15] = q; }
    __syncthreads();
    if (t < 16) {
        float S = reds[0][t] + reds[1][t] + reds[2][t] + reds[3][t];
        float Q = redq[0][t] + redq[1][t] + redq[2][t] + redq[3][t];
        part2[(size_t)t * NBLK + blockIdx.x]          = S;
        part2[(size_t)(16 + t) * NBLK + blockIdx.x]   = Q;
    }
}

// ---------------- K5: BN2 epilogue -> out[65536][10] fp32
__global__ void k_final(const float* __restrict__ oc, const float* __restrict__ st2,
                        const float* __restrict__ gamma2, const float* __restrict__ beta2,
                        float* __restrict__ out)
{
    int idx = blockIdx.x * 256 + threadIdx.x;    // 2560*256 == 655360 exactly
    int m = idx / 10;
    int k = idx - m * 10;
    float mean = st2[k] * (1.0f / 65536.0f);
    float var  = st2[16 + k] * (1.0f / 65536.0f) - mean * mean;
    float sc   = gamma2[k] / sqrtf(var + EPS);
    out[idx] = (oc[(size_t)m * NP2 + k] - mean) * sc + beta2[k];
}

extern "C" void kernel_launch(void* const* d_in, const int* in_sizes, int n_in,
                              void* d_out, int out_size, void* d_ws, size_t ws_size,
                              hipStream_t stream)
{
    const float* x      = (const float*)d_in[0];
    const float* W1     = (const float*)d_in[1];
    const float* gamma1 = (const float*)d_in[2];
    // d_in[3] = beta1 : algebraically cancels under BN2's mean subtraction
    const float* W2     = (const float*)d_in[4];
    const float* gamma2 = (const float*)d_in[5];
    const float* beta2  = (const float*)d_in[6];
    float* out = (float*)d_out;

    char* ws = (char*)d_ws;
    _Float16* S1    = (_Float16*)(ws + OFF_S1);
    _Float16* h     = (_Float16*)(ws + OFF_H);
    float*    st1   = (float*)(ws + OFF_ST1);
    _Float16* w2h   = (_Float16*)(ws + OFF_W2);
    float*    st2   = (float*)(ws + OFF_ST2);
    float*    oc    = (float*)(ws + OFF_OC);
    float*    part  = (float*)(ws + OFF_P1);   // aliases oc (time-disjoint)
    float*    part2 = (float*)(ws + OFF_P2);

    k_prep1 <<<1000, 256, 0, stream>>>(W1, S1);
    k_gemm1 <<<NBLK, 256, 0, stream>>>(x, S1, h, part);
    k_reduce<<<640, 256, 0, stream>>>(part, st1);
    k_prep2 <<<1, 320, 0, stream>>>(st1, gamma1, W2, w2h);
    k_gemm2 <<<NBLK, 256, 0, stream>>>(h, w2h, oc, part2);
    k_reduce<<<32, 256, 0, stream>>>(part2, st2);
    k_final <<<2560, 256, 0, stream>>>(oc, st2, gamma2, beta2, out);
}